// Round 12
// baseline (78.570 us; speedup 1.0000x reference)
//
#include <hip/hip_runtime.h>
#include <math.h>

#define NROWS 8192
#define D     64
#define BHALF 1024              // antithetic fold: b and b+1024 merged
#define ROWT  32                // rows per block (2 strips of 16)
#define NTILE (NROWS / ROWT)    // 256 blocks (1/CU)
#define WPB   16                // waves per block (1024 threads -> 4/SIMD)
#define BPW   (BHALF / WPB)     // 64 folded b per wave
#define NSTRIP (BPW / 16)       // 4 GEMM1 b-strips per wave

// g region (phase 1): 16 waves x 2 row-strips x 16 rows x 72 ushort
#define GSTRIDE  72
#define GPLANE   (16 * GSTRIDE)             // ushorts per strip plane (1152)
// reduce region (phase 2, overlays g): 16 planes x 32 rows x 66 f32
#define RSTRIDE  66
#define RPLANE   (32 * RSTRIDE)             // floats per plane (2112)
// size for the LARGER phase: reduce 16*2112*4 = 135168 B > g 73728 B
#define SMEM_BYTES (WPB * RPLANE * 4)       // 135168 B (<160 KiB/CU)

typedef short bf16x8 __attribute__((ext_vector_type(8)));
typedef float f32x4  __attribute__((ext_vector_type(4)));

__device__ __forceinline__ unsigned short f2bf(float f) {
    unsigned int u = __float_as_uint(f);
    u = (u + 0x7FFFu + ((u >> 16) & 1u)) >> 16;   // round-to-nearest-even
    return (unsigned short)u;
}
__device__ __forceinline__ float bf2f(unsigned short h) {
    return __uint_as_float(((unsigned int)h) << 16);
}

// v_sin/v_cos take revolutions; v_fract does the range reduction.
__device__ __forceinline__ void fast_sincos(float x, float* sn, float* cs) {
    float rev = x * 0.15915494309189535f;
    rev = __builtin_amdgcn_fractf(rev);
    *sn = __builtin_amdgcn_sinf(rev);
    *cs = __builtin_amdgcn_cosf(rev);
}

// ---------------------------------------------------------------------------
// Precompute (fold b>=1024 into b<1024: sim'=-sim, mat'=-mat):
//   ch[b][j] = bf16(eps[b][j]/lam[j])  (single bf16; sim=(xh+xl)*bh keeps x
//     at ~f32 precision — R11: absmax 0.0508 of 0.0638 budget, stable)
//   mat closed form, stored TRANSPOSED bf16 matT[i][b] (B-frag-ready)
//   w2s[b] = w[b]+w[b+1024], w2c[b] = w[2048+b]-w[3072+b]
// ---------------------------------------------------------------------------
__global__ void ssgp_precompute(const float* __restrict__ eps,
                                const float* __restrict__ lam,
                                const float* __restrict__ eta,
                                const float* __restrict__ w,
                                unsigned short* __restrict__ ch,
                                unsigned short* __restrict__ matT,
                                float* __restrict__ w2s,
                                float* __restrict__ w2c) {
    int idx = blockIdx.x * 256 + threadIdx.x;      // b*64 + i, b < 1024
    int b = idx >> 6;
    int i = idx & 63;
    float e2 = eta[0] * eta[0];
    float c = eps[idx] / lam[i];
    ch[idx] = f2bf(c);
    float m;
    if (i < 32) m =  eps[b * D + i + 32] / lam[i + 32];
    else        m = -eps[b * D + i - 32] / lam[i - 32] - e2 * c;
    matT[i * BHALF + b] = f2bf(m);
    if (i == 0) {
        w2s[b] = w[b] + w[b + BHALF];
        w2c[b] = w[2048 + b] - w[3072 + b];
    }
}

// ---------------------------------------------------------------------------
// Fused, block-complete, 32-row tiles, 16-wave blocks (R12): same per-load
// reuse as R10/R11 (each bh/mf feeds 2 row strips) but waves/SIMD 2 -> 4 so
// sincos-VALU of some waves overlaps MFMA/L2 of others (m114). Each wave
// owns a 64-b slice: 4 b-strips GEMM1 -> sincos/scale -> 2 LDS g planes ->
// GEMM2 K=64 -> 16-plane LDS block reduce -> direct out store.
// NOTE: 16-wave block forces VGPR <= 128. If VGPR_Count collapses (R5-style
// scratch demotion), revert to the R11 512-thread version.
// No partials/atomics/fences (R5/R6: fence split-K cost ~110 us).
// Layouts (verified m89/m91/m120):
//   C/D:      col = lane&15, row = (lane>>4)*4 + reg
//   A/B-frag: [m|n = lane&15][k = (lane>>4)*8 + j], 8 contiguous bf16 in k
// ---------------------------------------------------------------------------
__global__ __launch_bounds__(1024) void ssgp_main(
        const float* __restrict__ x,
        const unsigned short* __restrict__ ch,
        const unsigned short* __restrict__ matT,
        const float* __restrict__ w2s,
        const float* __restrict__ w2c,
        float* __restrict__ out) {
    __shared__ __align__(16) unsigned char smem[SMEM_BYTES];
    unsigned short* g_lds = (unsigned short*)smem;   // phase 1 (73728 B)
    float*          red   = (float*)smem;            // phase 2 (135168 B)

    const int t    = threadIdx.x;
    const int wv   = t >> 6;            // 0..15
    const int lane = t & 63;
    const int l15  = lane & 15;
    const int q    = lane >> 4;
    const int rbase = blockIdx.x * ROWT;

    // x A-frags for both row strips: row = rbase + s*16 + l15,
    // k = kc*32 + q*8 + j; split hi/lo bf16 (x stays ~f32-accurate)
    bf16x8 xh[2][2], xl[2][2];          // [strip][kc]
    #pragma unroll
    for (int s = 0; s < 2; ++s) {
        const float* xp = x + (size_t)(rbase + s * 16 + l15) * D + q * 8;
        #pragma unroll
        for (int kc = 0; kc < 2; ++kc) {
            #pragma unroll
            for (int e = 0; e < 8; ++e) {
                float f = xp[kc * 32 + e];
                unsigned short h = f2bf(f);
                xh[s][kc][e] = (short)h;
                xl[s][kc][e] = (short)f2bf(f - bf2f(h));
            }
        }
    }

    f32x4 facc[2][4];
    #pragma unroll
    for (int s = 0; s < 2; ++s)
        #pragma unroll
        for (int si = 0; si < 4; ++si) facc[s][si] = f32x4{0.f, 0.f, 0.f, 0.f};

    unsigned short* gw = g_lds + wv * (2 * GPLANE);  // wave's 2 g planes
    const int b0 = wv * BPW;

    // ---- GEMM1: 4 b-strips; bh loaded once, used by both row strips
    #pragma unroll
    for (int st = 0; st < NSTRIP; ++st) {
        const int brow = b0 + st * 16 + l15;
        const unsigned short* cph = ch + (size_t)brow * D + q * 8;
        f32x4 sim0 = f32x4{0.f, 0.f, 0.f, 0.f};
        f32x4 sim1 = f32x4{0.f, 0.f, 0.f, 0.f};
        #pragma unroll
        for (int kc = 0; kc < 2; ++kc) {
            bf16x8 bh = *(const bf16x8*)(cph + kc * 32);
            sim0 = __builtin_amdgcn_mfma_f32_16x16x32_bf16(xh[0][kc], bh, sim0, 0, 0, 0);
            sim0 = __builtin_amdgcn_mfma_f32_16x16x32_bf16(xl[0][kc], bh, sim0, 0, 0, 0);
            sim1 = __builtin_amdgcn_mfma_f32_16x16x32_bf16(xh[1][kc], bh, sim1, 0, 0, 0);
            sim1 = __builtin_amdgcn_mfma_f32_16x16x32_bf16(xl[1][kc], bh, sim1, 0, 0, 0);
        }
        const float ws = w2s[brow];
        const float wc = w2c[brow];
        #pragma unroll
        for (int r = 0; r < 4; ++r) {
            float sn, cs;
            fast_sincos(sim0[r], &sn, &cs);
            gw[(q * 4 + r) * GSTRIDE + st * 16 + l15] = f2bf(cs * wc - sn * ws);
            fast_sincos(sim1[r], &sn, &cs);
            gw[GPLANE + (q * 4 + r) * GSTRIDE + st * 16 + l15] = f2bf(cs * wc - sn * ws);
        }
    }
    // same-wave LDS RAW -> compiler inserts lgkmcnt wait; no barrier

    // ---- GEMM2: F_s(16x64) += G_s(16x64) * matT^T  (K = 64); mf shared
    #pragma unroll
    for (int kc2 = 0; kc2 < 2; ++kc2) {
        bf16x8 gf0 = *(const bf16x8*)(gw + l15 * GSTRIDE + kc2 * 32 + q * 8);
        bf16x8 gf1 = *(const bf16x8*)(gw + GPLANE + l15 * GSTRIDE + kc2 * 32 + q * 8);
        #pragma unroll
        for (int si = 0; si < 4; ++si) {
            const unsigned short* mp =
                matT + (size_t)(si * 16 + l15) * BHALF + b0 + kc2 * 32 + q * 8;
            bf16x8 mf = *(const bf16x8*)mp;
            facc[0][si] = __builtin_amdgcn_mfma_f32_16x16x32_bf16(gf0, mf, facc[0][si], 0, 0, 0);
            facc[1][si] = __builtin_amdgcn_mfma_f32_16x16x32_bf16(gf1, mf, facc[1][si], 0, 0, 0);
        }
    }

    // ---- block reduce of the 16 wave tiles (LDS, overlaying g region)
    __syncthreads();    // all waves done reading their g tiles
    {
        float* rp = red + wv * RPLANE;
        #pragma unroll
        for (int s = 0; s < 2; ++s)
            #pragma unroll
            for (int si = 0; si < 4; ++si)
                #pragma unroll
                for (int r = 0; r < 4; ++r)
                    rp[(s * 16 + q * 4 + r) * RSTRIDE + si * 16 + l15] =
                        facc[s][si][r];
    }
    __syncthreads();
    {
        // 2048 outputs, 1024 threads -> one float2 each
        const int row = t >> 5;          // 0..31
        const int col = (t & 31) * 2;    // 0..62
        float sx = 0.f, sy = 0.f;
        #pragma unroll
        for (int p = 0; p < WPB; ++p) {
            const float* rp = red + p * RPLANE + row * RSTRIDE + col;
            sx += rp[0];
            sy += rp[1];
        }
        float2 v; v.x = sx; v.y = sy;
        *(float2*)(out + (size_t)(rbase + row) * D + col) = v;
    }
}

extern "C" void kernel_launch(void* const* d_in, const int* in_sizes, int n_in,
                              void* d_out, int out_size, void* d_ws, size_t ws_size,
                              hipStream_t stream) {
    // setup_inputs order: t, x, epsilon, lam, eta, w
    const float* x   = (const float*)d_in[1];
    const float* eps = (const float*)d_in[2];
    const float* lam = (const float*)d_in[3];
    const float* eta = (const float*)d_in[4];
    const float* w   = (const float*)d_in[5];
    float* out = (float*)d_out;

    unsigned short* ch   = (unsigned short*)d_ws;          // 1024*64 ushort
    unsigned short* matT = ch + BHALF * D;                 // 1024*64 ushort
    float* w2s = (float*)(matT + BHALF * D);               // 1024 f32
    float* w2c = w2s + BHALF;

    ssgp_precompute<<<(BHALF * D) / 256, 256, 0, stream>>>(
        eps, lam, eta, w, ch, matT, w2s, w2c);

    ssgp_main<<<NTILE, 1024, 0, stream>>>(x, ch, matT, w2s, w2c, out);
}

// Round 13
// 76.818 us; speedup vs baseline: 1.0228x; 1.0228x over previous
//
#include <hip/hip_runtime.h>
#include <math.h>

#define NROWS 8192
#define D     64
#define BHALF 1024              // antithetic fold: b and b+1024 merged
#define ROWT  32                // rows per block (2 strips of 16, all waves)
#define NTILE (NROWS / ROWT)    // 256 blocks (1/CU)
#define WPB   8                 // waves per block
#define BPW   (BHALF / WPB)     // 128 folded b per wave
#define NSTRIP (BPW / 16)       // 8 GEMM1 b-strips per wave

// g region (phase 1): 8 waves x 2 row-strips x 16 rows x 136 ushort
#define GSTRIDE  136
#define GPLANE   (16 * GSTRIDE)             // ushorts per strip plane (2176)
#define SMEM_BYTES (WPB * 2 * GPLANE * 2)   // 69632 B
// reduce region (phase 2, overlays g): 8 planes x 32 rows x 66 f32 = 67584 B
#define RSTRIDE  66
#define RPLANE   (32 * RSTRIDE)

// R12 POST-MORTEM (do not retry): 16-wave/1024-thread blocks (4 waves/SIMD)
// regressed 77.3 -> 78.6 us — 135 KB LDS still capped at 1 block/CU, reduce
// tail doubled (16 planes vs 8), barrier cost up. R9 (chunk-WAR removal) was
// neutral. Main's residual ~4 us over floor is per-wave critical-path
// (GEMM1 MFMA -> sincos chain -> GEMM2), not occupancy or LDS ordering.

typedef short bf16x8 __attribute__((ext_vector_type(8)));
typedef float f32x4  __attribute__((ext_vector_type(4)));

__device__ __forceinline__ unsigned short f2bf(float f) {
    unsigned int u = __float_as_uint(f);
    u = (u + 0x7FFFu + ((u >> 16) & 1u)) >> 16;   // round-to-nearest-even
    return (unsigned short)u;
}
__device__ __forceinline__ float bf2f(unsigned short h) {
    return __uint_as_float(((unsigned int)h) << 16);
}

// v_sin/v_cos take revolutions; v_fract does the range reduction.
__device__ __forceinline__ void fast_sincos(float x, float* sn, float* cs) {
    float rev = x * 0.15915494309189535f;
    rev = __builtin_amdgcn_fractf(rev);
    *sn = __builtin_amdgcn_sinf(rev);
    *cs = __builtin_amdgcn_cosf(rev);
}

// ---------------------------------------------------------------------------
// Precompute (fold b>=1024 into b<1024: sim'=-sim, mat'=-mat):
//   ch[b][j] = bf16(eps[b][j]/lam[j])   (single bf16 — R11 dropped the cl
//     low word: sim = (xh+xl)*bh keeps x at ~f32 precision, c at bf16;
//     absmax 0.0508 of 0.0638 budget, stable/deterministic)
//   mat closed form, stored TRANSPOSED bf16 matT[i][b] (B-frag-ready)
//   w2s[b] = w[b]+w[b+1024], w2c[b] = w[2048+b]-w[3072+b]
// ---------------------------------------------------------------------------
__global__ void ssgp_precompute(const float* __restrict__ eps,
                                const float* __restrict__ lam,
                                const float* __restrict__ eta,
                                const float* __restrict__ w,
                                unsigned short* __restrict__ ch,
                                unsigned short* __restrict__ matT,
                                float* __restrict__ w2s,
                                float* __restrict__ w2c) {
    int idx = blockIdx.x * 256 + threadIdx.x;      // b*64 + i, b < 1024
    int b = idx >> 6;
    int i = idx & 63;
    float e2 = eta[0] * eta[0];
    float c = eps[idx] / lam[i];
    ch[idx] = f2bf(c);
    float m;
    if (i < 32) m =  eps[b * D + i + 32] / lam[i + 32];
    else        m = -eps[b * D + i - 32] / lam[i - 32] - e2 * c;
    matT[i * BHALF + b] = f2bf(m);
    if (i == 0) {
        w2s[b] = w[b] + w[b + BHALF];
        w2c[b] = w[2048 + b] - w[3072 + b];
    }
}

// ---------------------------------------------------------------------------
// Fused, block-complete, 32-row tiles: each wave applies its 128-b slice to
// TWO 16-row strips (every bh/mf fragment load feeds 2x the MFMAs — the
// R10 lever: 90.6->80.3). 2-pass split GEMM1 (xh+xl)*bh (R11: 80.3->77.3).
// Flow per wave: 8 b-strips [load bh once -> 4 sim MFMAs x 2 row strips]
// -> sincos/scale -> 2 LDS g planes (C/D -> A-frag swap) -> GEMM2 K=128
// (mf shared across strips) -> LDS block reduce -> direct out store.
// No partials/atomics/fences (R5/R6: fence split-K cost ~110 us).
// Layouts (verified m89/m91/m120):
//   C/D:      col = lane&15, row = (lane>>4)*4 + reg
//   A/B-frag: [m|n = lane&15][k = (lane>>4)*8 + j], 8 contiguous bf16 in k
// ---------------------------------------------------------------------------
__global__ __launch_bounds__(512) void ssgp_main(
        const float* __restrict__ x,
        const unsigned short* __restrict__ ch,
        const unsigned short* __restrict__ matT,
        const float* __restrict__ w2s,
        const float* __restrict__ w2c,
        float* __restrict__ out) {
    __shared__ __align__(16) unsigned char smem[SMEM_BYTES];
    unsigned short* g_lds = (unsigned short*)smem;   // phase 1 (69632 B)
    float*          red   = (float*)smem;            // phase 2 (67584 B)

    const int t    = threadIdx.x;
    const int wv   = t >> 6;            // 0..7
    const int lane = t & 63;
    const int l15  = lane & 15;
    const int q    = lane >> 4;
    const int rbase = blockIdx.x * ROWT;

    // x A-frags for both row strips: row = rbase + s*16 + l15,
    // k = kc*32 + q*8 + j; split hi/lo bf16 (x stays ~f32-accurate)
    bf16x8 xh[2][2], xl[2][2];          // [strip][kc]
    #pragma unroll
    for (int s = 0; s < 2; ++s) {
        const float* xp = x + (size_t)(rbase + s * 16 + l15) * D + q * 8;
        #pragma unroll
        for (int kc = 0; kc < 2; ++kc) {
            #pragma unroll
            for (int e = 0; e < 8; ++e) {
                float f = xp[kc * 32 + e];
                unsigned short h = f2bf(f);
                xh[s][kc][e] = (short)h;
                xl[s][kc][e] = (short)f2bf(f - bf2f(h));
            }
        }
    }

    f32x4 facc[2][4];
    #pragma unroll
    for (int s = 0; s < 2; ++s)
        #pragma unroll
        for (int si = 0; si < 4; ++si) facc[s][si] = f32x4{0.f, 0.f, 0.f, 0.f};

    unsigned short* gw = g_lds + wv * (2 * GPLANE);  // wave's 2 g planes
    const int b0 = wv * BPW;

    // ---- GEMM1: 8 b-strips; bh loaded once, used by both row strips
    #pragma unroll
    for (int st = 0; st < NSTRIP; ++st) {
        const int brow = b0 + st * 16 + l15;
        const unsigned short* cph = ch + (size_t)brow * D + q * 8;
        f32x4 sim0 = f32x4{0.f, 0.f, 0.f, 0.f};
        f32x4 sim1 = f32x4{0.f, 0.f, 0.f, 0.f};
        #pragma unroll
        for (int kc = 0; kc < 2; ++kc) {
            bf16x8 bh = *(const bf16x8*)(cph + kc * 32);
            sim0 = __builtin_amdgcn_mfma_f32_16x16x32_bf16(xh[0][kc], bh, sim0, 0, 0, 0);
            sim0 = __builtin_amdgcn_mfma_f32_16x16x32_bf16(xl[0][kc], bh, sim0, 0, 0, 0);
            sim1 = __builtin_amdgcn_mfma_f32_16x16x32_bf16(xh[1][kc], bh, sim1, 0, 0, 0);
            sim1 = __builtin_amdgcn_mfma_f32_16x16x32_bf16(xl[1][kc], bh, sim1, 0, 0, 0);
        }
        const float ws = w2s[brow];
        const float wc = w2c[brow];
        #pragma unroll
        for (int r = 0; r < 4; ++r) {
            float sn, cs;
            fast_sincos(sim0[r], &sn, &cs);
            gw[(q * 4 + r) * GSTRIDE + st * 16 + l15] = f2bf(cs * wc - sn * ws);
            fast_sincos(sim1[r], &sn, &cs);
            gw[GPLANE + (q * 4 + r) * GSTRIDE + st * 16 + l15] = f2bf(cs * wc - sn * ws);
        }
    }
    // same-wave LDS RAW -> compiler inserts lgkmcnt wait; no barrier

    // ---- GEMM2: F_s(16x64) += G_s(16x128) * matT^T; mf shared across s
    #pragma unroll
    for (int kc2 = 0; kc2 < 4; ++kc2) {
        bf16x8 gf0 = *(const bf16x8*)(gw + l15 * GSTRIDE + kc2 * 32 + q * 8);
        bf16x8 gf1 = *(const bf16x8*)(gw + GPLANE + l15 * GSTRIDE + kc2 * 32 + q * 8);
        #pragma unroll
        for (int si = 0; si < 4; ++si) {
            const unsigned short* mp =
                matT + (size_t)(si * 16 + l15) * BHALF + b0 + kc2 * 32 + q * 8;
            bf16x8 mf = *(const bf16x8*)mp;
            facc[0][si] = __builtin_amdgcn_mfma_f32_16x16x32_bf16(gf0, mf, facc[0][si], 0, 0, 0);
            facc[1][si] = __builtin_amdgcn_mfma_f32_16x16x32_bf16(gf1, mf, facc[1][si], 0, 0, 0);
        }
    }

    // ---- block reduce of the 8 wave tiles (LDS, overlaying g region)
    __syncthreads();    // all waves done reading their g tiles
    {
        float* rp = red + wv * RPLANE;
        #pragma unroll
        for (int s = 0; s < 2; ++s)
            #pragma unroll
            for (int si = 0; si < 4; ++si)
                #pragma unroll
                for (int r = 0; r < 4; ++r)
                    rp[(s * 16 + q * 4 + r) * RSTRIDE + si * 16 + l15] =
                        facc[s][si][r];
    }
    __syncthreads();
    {
        // 2048 outputs, 512 threads -> one float4 each
        const int row = t >> 4;          // 0..31
        const int col = (t & 15) * 4;    // 0..60
        float4 a; a.x = a.y = a.z = a.w = 0.f;
        #pragma unroll
        for (int p = 0; p < WPB; ++p) {
            const float* rp = red + p * RPLANE + row * RSTRIDE + col;
            a.x += rp[0]; a.y += rp[1]; a.z += rp[2]; a.w += rp[3];
        }
        *(float4*)(out + (size_t)(rbase + row) * D + col) = a;
    }
}

extern "C" void kernel_launch(void* const* d_in, const int* in_sizes, int n_in,
                              void* d_out, int out_size, void* d_ws, size_t ws_size,
                              hipStream_t stream) {
    // setup_inputs order: t, x, epsilon, lam, eta, w
    const float* x   = (const float*)d_in[1];
    const float* eps = (const float*)d_in[2];
    const float* lam = (const float*)d_in[3];
    const float* eta = (const float*)d_in[4];
    const float* w   = (const float*)d_in[5];
    float* out = (float*)d_out;

    unsigned short* ch   = (unsigned short*)d_ws;          // 1024*64 ushort
    unsigned short* matT = ch + BHALF * D;                 // 1024*64 ushort
    float* w2s = (float*)(matT + BHALF * D);               // 1024 f32
    float* w2c = w2s + BHALF;

    ssgp_precompute<<<(BHALF * D) / 256, 256, 0, stream>>>(
        eps, lam, eta, w, ch, matT, w2s, w2c);

    ssgp_main<<<NTILE, 512, 0, stream>>>(x, ch, matT, w2s, w2c, out);
}